// Round 1
// baseline (204.282 us; speedup 1.0000x reference)
//
#include <hip/hip_runtime.h>
#include <stdint.h>

// EnergyWell, round 8: R7 structure unchanged; ALL input loads marked
// non-temporal (nt). Theory: read-once data allocating into L2+L3 is the
// serialization point (fills write at 7.0 TB/s on the same fabric while our
// reads pin at ~3 TB/s -> not a symmetric fabric cap). nt bypasses cache
// allocation for a stream that is dead-on-arrival anyway.
// Single-variable probe: if dur_us unchanged, read ceiling is structural
// and the session concludes at the roofline.

#define C_WELLS 64

typedef int   v4i __attribute__((ext_vector_type(4)));
typedef float v2f __attribute__((ext_vector_type(2)));

template <int CTRL>
__device__ __forceinline__ unsigned long long dpp64(unsigned long long k) {
    int lo = (int)(unsigned)k;
    int hi = (int)(unsigned)(k >> 32);
    lo = __builtin_amdgcn_update_dpp(0, lo, CTRL, 0xF, 0xF, true);
    hi = __builtin_amdgcn_update_dpp(0, hi, CTRL, 0xF, 0xF, true);
    return ((unsigned long long)(unsigned)hi << 32) | (unsigned)lo;
}

__device__ __forceinline__ unsigned long long umin64(unsigned long long a,
                                                     unsigned long long b) {
    return a < b ? a : b;   // v_cmp_lt_u64 + 2 cndmask
}

__global__ __launch_bounds__(256, 8)
void energy_well_kernel(const v2f* __restrict__ inst_pos,   // N
                        const v2f* __restrict__ half_sizes, // N
                        const float* __restrict__ well_boxes,// 64*4 {xl,yl,xh,yh}
                        const v4i*  __restrict__ avail4,    // N*16
                        const float* __restrict__ exponents, // N
                        float* __restrict__ out,             // N
                        int N, int nT16)
{
    const int lane = threadIdx.x & 63;
    const int sub  = lane & 3;                 // quad member: wells [16sub,16sub+16)
    const int tile = (int)((blockIdx.x * blockDim.x + threadIdx.x) >> 6);
    if (tile >= nT16) return;

    const int i  = tile * 16 + (lane >> 2);    // this quad's instance
    const int ii = i < N ? i : N - 1;          // clamp (tail safety)

    // ---- issue all loads up front (7 VMEM, independent, all non-temporal) ----
    const v4i* a = avail4 + ((size_t)ii * 16 + (size_t)sub * 4);
    const v4i av0 = __builtin_nontemporal_load(a + 0);
    const v4i av1 = __builtin_nontemporal_load(a + 1);
    const v4i av2 = __builtin_nontemporal_load(a + 2);
    const v4i av3 = __builtin_nontemporal_load(a + 3);
    const v2f p = __builtin_nontemporal_load(inst_pos + ii);
    const v2f h = __builtin_nontemporal_load(half_sizes + ii);
    const float e = __builtin_nontemporal_load(exponents + ii);

    // x-edges: wave-uniform, compile-time offsets -> s_load (stay in SGPRs)
    // (reused by every wave -> keep these NORMAL cached loads)
    float xlv[8], xhv[8];
    #pragma unroll
    for (int ix = 0; ix < 8; ++ix) {
        xlv[ix] = well_boxes[4 * ix + 0];
        xhv[ix] = well_boxes[4 * ix + 2];
    }
    // this lane's two y-rows (iy = 2*sub, 2*sub+1)
    const float ylA = well_boxes[64 * sub + 1];
    const float yhA = well_boxes[64 * sub + 3];
    const float ylB = well_boxes[64 * sub + 33];
    const float yhB = well_boxes[64 * sub + 35];

    // ---- per-instance separable distances ----
    const float xm = p.x - h.x, xp_ = p.x + h.x;
    const float ym = p.y - h.y, yp_ = p.y + h.y;

    float dxv[8];
    #pragma unroll
    for (int ix = 0; ix < 8; ++ix)
        dxv[ix] = fmaxf(fmaxf(xlv[ix] - xm, xp_ - xhv[ix]), 0.0f);  // v_max3
    const float dyA = fmaxf(fmaxf(ylA - ym, yp_ - yhA), 0.0f);
    const float dyB = fmaxf(fmaxf(ylB - ym, yp_ - yhB), 0.0f);

    // ---- keyed scan: 2 independent chains of 8, then merge (register-lean) ----
    const unsigned gbase = (unsigned)(sub << 4);
    unsigned long long acc0 = ~0ull, acc1 = ~0ull;
    #pragma unroll
    for (int j = 0; j < 4; ++j) {
        const v4i a4 = (j == 0) ? av0 : (j == 1) ? av1 : (j == 2) ? av2 : av3;
        #pragma unroll
        for (int k = 0; k < 4; ++k) {
            const int c2 = 4 * j + k;                   // local well 0..15
            const int avw = (k == 0) ? a4.x : (k == 1) ? a4.y
                          : (k == 2) ? a4.z : a4.w;
            const float dy   = (c2 < 8) ? dyA : dyB;
            const float dist = dxv[c2 & 7] + dy;
            unsigned long long key =
                (((unsigned long long)__float_as_uint(dist)) << 6)
                | (unsigned long long)(gbase + (unsigned)c2);
            key = avw ? key : ~0ull;                    // mask unavailable
            if (c2 & 1) acc1 = umin64(acc1, key);       // 2 parallel chains
            else        acc0 = umin64(acc0, key);
        }
    }
    unsigned long long kmin = umin64(acc0, acc1);

    // ---- cross-sub (quad) reduce on the VALU pipe via DPP ----
    kmin = umin64(kmin, dpp64<0xB1>(kmin));   // quad_perm [1,0,3,2] : xor 1
    kmin = umin64(kmin, dpp64<0x4E>(kmin));   // quad_perm [2,3,0,1] : xor 2

    // ---- decode winner and store ----
    const int g = (int)(kmin & 63);           // global well index of the min
    const int s = g & 7;                      // ix
    float a0 = (s & 1) ? dxv[1] : dxv[0];
    float a1 = (s & 1) ? dxv[3] : dxv[2];
    float a2 = (s & 1) ? dxv[5] : dxv[4];
    float a3 = (s & 1) ? dxv[7] : dxv[6];
    float b0 = (s & 2) ? a1 : a0;
    float b1 = (s & 2) ? a3 : a2;
    const float dxs = (s & 4) ? b1 : b0;
    const float dys = (g & 8) ? dyB : dyA;    // valid on the winner's sub

    if (((g >> 4) == sub) && (i < N)) {       // unique winner lane per quad
        float energy;
        if (e == 2.0f) energy = dxs * dxs + dys * dys;
        else           energy = powf(dxs, e) + powf(dys, e);
        __builtin_nontemporal_store(energy, out + i);
    }
}

extern "C" void kernel_launch(void* const* d_in, const int* in_sizes, int n_in,
                              void* d_out, int out_size, void* d_ws, size_t ws_size,
                              hipStream_t stream)
{
    // 0: inst_pos (N*2 f32), 1: half_inst_sizes (N*2 f32), 2: inst_areas (UNUSED),
    // 3: well_boxes (64*4 f32), 4: inst_cr_avail_map (N*64 int), 5: exponents (N)
    const v2f*  inst_pos   = (const v2f*)d_in[0];
    const v2f*  half_sizes = (const v2f*)d_in[1];
    const float* well_boxes = (const float*)d_in[3];
    const v4i*  avail4     = (const v4i*)d_in[4];
    const float* exponents  = (const float*)d_in[5];
    float* out = (float*)d_out;

    const int N = in_sizes[5];
    const int nT16 = (N + 15) / 16;            // one 16-instance tile per wave
    const int blocks = (nT16 + 3) / 4;         // 4 waves/block

    energy_well_kernel<<<dim3(blocks), dim3(256), 0, stream>>>(
        inst_pos, half_sizes, well_boxes, avail4, exponents, out, N, nT16);
}

// Round 2
// 196.793 us; speedup vs baseline: 1.0381x; 1.0381x over previous
//
#include <hip/hip_runtime.h>
#include <stdint.h>

// EnergyWell, round 9: REVERT to the R7/best configuration (192.3 us).
// R8's non-temporal probe regressed (204 vs 193) -> cache-allocation theory
// falsified. Evidence ledger for the ~3 TB/s read ceiling:
//   - R4-R6: layout/persistence/VALU variants -> ~2.6 TB/s, no change
//   - R7: 32 waves/CU (1.33x in-flight) -> no change (MLP not the limit)
//   - R8: nt loads (no L2/L3 allocation) -> slight regression
//   - runtime copyBuffer on the same data: 3.4 TB/s combined (external
//     known-good kernel in the same regime); fills are write-only at 6.9
// Conclusion: streaming-read path ~3 TB/s is structural; kernel ~46 us =
// 138 MB mandatory read at that rate; the rest of the graded 193 us is
// harness re-poison (2 x 74 us fills). This is the terminal configuration.

#define C_WELLS 64

template <int CTRL>
__device__ __forceinline__ unsigned long long dpp64(unsigned long long k) {
    int lo = (int)(unsigned)k;
    int hi = (int)(unsigned)(k >> 32);
    lo = __builtin_amdgcn_update_dpp(0, lo, CTRL, 0xF, 0xF, true);
    hi = __builtin_amdgcn_update_dpp(0, hi, CTRL, 0xF, 0xF, true);
    return ((unsigned long long)(unsigned)hi << 32) | (unsigned)lo;
}

__device__ __forceinline__ unsigned long long umin64(unsigned long long a,
                                                     unsigned long long b) {
    return a < b ? a : b;   // v_cmp_lt_u64 + 2 cndmask
}

__global__ __launch_bounds__(256, 8)
void energy_well_kernel(const float2* __restrict__ inst_pos,   // N
                        const float2* __restrict__ half_sizes, // N
                        const float*  __restrict__ well_boxes, // 64*4 {xl,yl,xh,yh}
                        const int4*   __restrict__ avail4,     // N*16
                        const float*  __restrict__ exponents,  // N
                        float* __restrict__ out,               // N
                        int N, int nT16)
{
    const int lane = threadIdx.x & 63;
    const int sub  = lane & 3;                 // quad member: wells [16sub,16sub+16)
    const int tile = (int)((blockIdx.x * blockDim.x + threadIdx.x) >> 6);
    if (tile >= nT16) return;

    const int i  = tile * 16 + (lane >> 2);    // this quad's instance
    const int ii = i < N ? i : N - 1;          // clamp (tail safety)

    // ---- issue all loads up front (7 VMEM, independent) ----
    const int4* a = avail4 + ((size_t)ii * 16 + (size_t)sub * 4);
    const int4 av0 = a[0], av1 = a[1], av2 = a[2], av3 = a[3];
    const float2 p = inst_pos[ii];
    const float2 h = half_sizes[ii];
    const float  e = exponents[ii];

    // x-edges: wave-uniform, compile-time offsets -> s_load (stay in SGPRs)
    float xlv[8], xhv[8];
    #pragma unroll
    for (int ix = 0; ix < 8; ++ix) {
        xlv[ix] = well_boxes[4 * ix + 0];
        xhv[ix] = well_boxes[4 * ix + 2];
    }
    // this lane's two y-rows (iy = 2*sub, 2*sub+1)
    const float ylA = well_boxes[64 * sub + 1];
    const float yhA = well_boxes[64 * sub + 3];
    const float ylB = well_boxes[64 * sub + 33];
    const float yhB = well_boxes[64 * sub + 35];

    // ---- per-instance separable distances ----
    const float xm = p.x - h.x, xp_ = p.x + h.x;
    const float ym = p.y - h.y, yp_ = p.y + h.y;

    float dxv[8];
    #pragma unroll
    for (int ix = 0; ix < 8; ++ix)
        dxv[ix] = fmaxf(fmaxf(xlv[ix] - xm, xp_ - xhv[ix]), 0.0f);  // v_max3
    const float dyA = fmaxf(fmaxf(ylA - ym, yp_ - yhA), 0.0f);
    const float dyB = fmaxf(fmaxf(ylB - ym, yp_ - yhB), 0.0f);

    // ---- keyed scan: 2 independent chains of 8, then merge (register-lean) ----
    const unsigned gbase = (unsigned)(sub << 4);
    unsigned long long acc0 = ~0ull, acc1 = ~0ull;
    #pragma unroll
    for (int j = 0; j < 4; ++j) {
        const int4 a4 = (j == 0) ? av0 : (j == 1) ? av1 : (j == 2) ? av2 : av3;
        #pragma unroll
        for (int k = 0; k < 4; ++k) {
            const int c2 = 4 * j + k;                   // local well 0..15
            const int avw = (k == 0) ? a4.x : (k == 1) ? a4.y
                          : (k == 2) ? a4.z : a4.w;
            const float dy   = (c2 < 8) ? dyA : dyB;
            const float dist = dxv[c2 & 7] + dy;
            unsigned long long key =
                (((unsigned long long)__float_as_uint(dist)) << 6)
                | (unsigned long long)(gbase + (unsigned)c2);
            key = avw ? key : ~0ull;                    // mask unavailable
            if (c2 & 1) acc1 = umin64(acc1, key);       // 2 parallel chains
            else        acc0 = umin64(acc0, key);
        }
    }
    unsigned long long kmin = umin64(acc0, acc1);

    // ---- cross-sub (quad) reduce on the VALU pipe via DPP ----
    kmin = umin64(kmin, dpp64<0xB1>(kmin));   // quad_perm [1,0,3,2] : xor 1
    kmin = umin64(kmin, dpp64<0x4E>(kmin));   // quad_perm [2,3,0,1] : xor 2

    // ---- decode winner and store ----
    const int g = (int)(kmin & 63);           // global well index of the min
    const int s = g & 7;                      // ix
    float a0 = (s & 1) ? dxv[1] : dxv[0];
    float a1 = (s & 1) ? dxv[3] : dxv[2];
    float a2 = (s & 1) ? dxv[5] : dxv[4];
    float a3 = (s & 1) ? dxv[7] : dxv[6];
    float b0 = (s & 2) ? a1 : a0;
    float b1 = (s & 2) ? a3 : a2;
    const float dxs = (s & 4) ? b1 : b0;
    const float dys = (g & 8) ? dyB : dyA;    // valid on the winner's sub

    if (((g >> 4) == sub) && (i < N)) {       // unique winner lane per quad
        float energy;
        if (e == 2.0f) energy = dxs * dxs + dys * dys;
        else           energy = powf(dxs, e) + powf(dys, e);
        out[i] = energy;
    }
}

extern "C" void kernel_launch(void* const* d_in, const int* in_sizes, int n_in,
                              void* d_out, int out_size, void* d_ws, size_t ws_size,
                              hipStream_t stream)
{
    // 0: inst_pos (N*2 f32), 1: half_inst_sizes (N*2 f32), 2: inst_areas (UNUSED),
    // 3: well_boxes (64*4 f32), 4: inst_cr_avail_map (N*64 int), 5: exponents (N)
    const float2* inst_pos   = (const float2*)d_in[0];
    const float2* half_sizes = (const float2*)d_in[1];
    const float*  well_boxes = (const float*)d_in[3];
    const int4*   avail4     = (const int4*)d_in[4];
    const float*  exponents  = (const float*)d_in[5];
    float* out = (float*)d_out;

    const int N = in_sizes[5];
    const int nT16 = (N + 15) / 16;            // one 16-instance tile per wave
    const int blocks = (nT16 + 3) / 4;         // 4 waves/block

    energy_well_kernel<<<dim3(blocks), dim3(256), 0, stream>>>(
        inst_pos, half_sizes, well_boxes, avail4, exponents, out, N, nT16);
}